// Round 2
// baseline (362.773 us; speedup 1.0000x reference)
//
#include <hip/hip_runtime.h>
#include <hip/hip_fp16.h>

// ---------------------------------------------------------------------------
// GCN forward on MI355X — round 20.
//  * Partition rewrite: the 6-kernel bucket/two-phase CSR build (bin_count,
//    totals, scan_bb, scanB, fill, build_csr) is replaced by a direct
//    per-node-cursor pipeline:
//      zero -> count(global atomicAdd deg[dst]) -> blocksum -> scan ->
//      rowbase(per-node padded offsets, rowinfo/xd/dinvh/pads) ->
//      place(pos = atomicAdd(cursor[dst]); csr[pos] = src | x[src]<<18)
//    Edge-list streams drop 5 -> 3; pairbuf (12.8 MB roundtrip), hist/cur
//    (4 MB) and both LDS-cursor stages disappear.  dst is uniform over 200k
//    nodes -> avg atomic contention 8, handled in L2 at near-stream rate.
//  * CSR output is bit-compatible (packed x<<18, sentinel N, pads to x4,
//    16-B-aligned rows) — layer1/layer2/final kernels unchanged from round
//    19 (219.6 us; partition block measured ~134 us incl. launch gaps).
// ---------------------------------------------------------------------------

#define DD 64            // feature dim
#define SRCMASK 0x3FFFF  // low 18 bits = src node id

typedef _Float16 half8_t __attribute__((ext_vector_type(8)));
typedef float float4_t __attribute__((ext_vector_type(4)));
union F4H8 { float4 f; half8_t h; };
union H8   { float4 f; __half2 h[4]; };

static __device__ __forceinline__ void atomAddF(float* p, float v) {
    unsafeAtomicAdd(p, v);   // global_atomic_add_f32 on gfx950
}

// ---- P0: zero deg + outacc ------------------------------------------------
__global__ __launch_bounds__(256) void zero_kernel(
        int* __restrict__ deg, float* __restrict__ outacc, int N, int G2) {
    int i = blockIdx.x * 256 + threadIdx.x;
    if (i < N) deg[i] = 0;
    if (i < G2) outacc[i] = 0.f;
}

// ---- P1: degree count (global atomics) + fp16 conversion piggy-backs ------
__global__ __launch_bounds__(256) void count_kernel(
        const int* __restrict__ dst, int E, int* __restrict__ deg,
        const float2* __restrict__ table2, __half2* __restrict__ th2, int n2,
        const float* __restrict__ W1, const float* __restrict__ W2,
        __half* __restrict__ w1t, __half* __restrict__ w2t) {
    int i0 = blockIdx.x * 256 + threadIdx.x;
    int stride = gridDim.x * 256;
    for (int i = i0; i < n2; i += stride)
        th2[i] = __float22half2_rn(table2[i]);
    for (int i = i0; i < DD * DD; i += stride) {
        int n = i >> 6, k = i & 63;
        w1t[i] = __float2half(W1[k * DD + n]);   // WT[n][k]
        w2t[i] = __float2half(W2[k * DD + n]);
    }
    for (int e = i0; e < E; e += stride)
        atomicAdd(&deg[dst[e]], 1);              // fire-and-forget
}

// ---- P2: per-block sums of padded degrees ---------------------------------
__global__ __launch_bounds__(256) void blocksum_kernel(
        const int* __restrict__ deg, int* __restrict__ bsum, int N) {
    __shared__ int wsum[4];
    int tid = threadIdx.x;
    int node = blockIdx.x * 256 + tid;
    int c = (node < N) ? deg[node] : 0;
    int pc = (c + 3) & ~3;
    #pragma unroll
    for (int off = 32; off >= 1; off >>= 1)
        pc += __shfl_xor(pc, off);
    if ((tid & 63) == 0) wsum[tid >> 6] = pc;
    __syncthreads();
    if (tid == 0) bsum[blockIdx.x] = wsum[0] + wsum[1] + wsum[2] + wsum[3];
}

// ---- P3: exclusive scan of bsum[KB] -> bbase ------------------------------
__global__ __launch_bounds__(256) void scan_kernel(
        const int* __restrict__ bsum, int* __restrict__ bbase, int K) {
    __shared__ int part[256];
    int tid = threadIdx.x;
    int CH2 = (K + 255) / 256;
    int base = tid * CH2;
    int s = 0;
    for (int i = 0; i < CH2; ++i) {
        int idx = base + i;
        if (idx < K) s += bsum[idx];
    }
    part[tid] = s;
    __syncthreads();
    if (tid < 64) {
        int carry = 0;
        for (int c = 0; c < 4; ++c) {
            int orig = part[c * 64 + tid];
            int v = orig;
            #pragma unroll
            for (int off = 1; off < 64; off <<= 1) {
                int t = __shfl_up(v, off);
                if (tid >= off) v += t;
            }
            int tot = __shfl(v, 63);
            part[c * 64 + tid] = v - orig + carry;   // exclusive
            carry += tot;
        }
    }
    __syncthreads();
    int run = part[tid];
    for (int i = 0; i < CH2; ++i) {
        int idx = base + i;
        if (idx < K) {
            bbase[idx] = run;
            run += bsum[idx];
        }
    }
}

// ---- P4: per-node row bases, rowinfo/xd/dinvh/cursor + sentinel pads ------
// csr entry = src | (x[src] << 18).  Sentinel pad = N (x-part 0 -> zeroed th
// row 0, dinvh[N] = 0 -> zero weight, g1h row N zeroed -> zero layer2 term).
__global__ __launch_bounds__(256) void rowbase_kernel(
        const int* __restrict__ deg, const int* __restrict__ bbase,
        const int* __restrict__ x, int2* __restrict__ rowinfo,
        float2* __restrict__ xd, __half* __restrict__ dinvh,
        int* __restrict__ cursor, int* __restrict__ csr,
        __half* __restrict__ g1h, int N) {
    __shared__ int basel[256], excl[256];
    int tid = threadIdx.x;
    int node = blockIdx.x * 256 + tid;
    int c = (node < N) ? deg[node] : 0;
    int pc = (c + 3) & ~3;              // padded count (multiple of 4)
    basel[tid] = pc;
    __syncthreads();
    if (tid < 64) {
        int carry = 0;
        for (int cc = 0; cc < 4; ++cc) {
            int orig = basel[cc * 64 + tid];
            int v = orig;
            #pragma unroll
            for (int off = 1; off < 64; off <<= 1) {
                int t = __shfl_up(v, off);
                if (tid >= off) v += t;
            }
            int tot = __shfl(v, 63);
            excl[cc * 64 + tid] = v - orig + carry;   // exclusive
            carry += tot;
        }
    }
    __syncthreads();
    int base = bbase[blockIdx.x] + excl[tid];
    if (node < N) {
        rowinfo[node] = make_int2(base, pc);
        float di = rsqrtf((float)c + 1.0f);
        xd[node] = make_float2(di, __int_as_float(x[node]));
        dinvh[node] = __float2half(di);
        cursor[node] = base;
        for (int t = c; t < pc; ++t) csr[base + t] = N;   // sentinel pad
    } else if (node == N) {
        xd[N] = make_float2(0.0f, __int_as_float(0));     // zero weight
        dinvh[N] = __float2half(0.0f);
        float2* z = (float2*)(g1h + (size_t)N * DD);      // zero row N
        for (int t = 0; t < DD / 4; ++t) z[t] = make_float2(0.f, 0.f);
    }
}

// ---- P5: direct placement via per-node cursors ----------------------------
__global__ __launch_bounds__(256) void place_kernel(
        const int* __restrict__ src, const int* __restrict__ dstp, int E,
        const int* __restrict__ x, int* __restrict__ cursor,
        int* __restrict__ csr) {
    int i0 = blockIdx.x * 256 + threadIdx.x;
    int stride = gridDim.x * 256;
    for (int e = i0; e < E; e += stride) {
        int s = src[e], d = dstp[e];
        int xs = x[s];                       // independent L2 gather
        int pos = atomicAdd(&cursor[d], 1);  // returns old
        csr[pos] = s | (xs << 18);
    }
}

// ---------------- layer 1: agg from fp16 table, MFMA MLP, g1h = f16(dv*h1) --
// 8 lanes/node, b128 chunks; unroll x2; Hs stride 9 (bank-conflict pad).
// Packed-CSR decode: th row = entry >> 18, weight = dinvh[entry & SRCMASK]
// (independent 2B load, issues concurrently with the 16B th4 gather).
__global__ __launch_bounds__(256, 8) void layer1_kernel(
        const int2* __restrict__ rowinfo,
        const int* __restrict__ csr_src, const float2* __restrict__ xd,
        const __half* __restrict__ dinvh,
        const float4* __restrict__ th4, const __half* __restrict__ wt,
        const float* __restrict__ bias, __half* __restrict__ g1h, int N) {
    __shared__ float4 Hs4[32 * 9];   // padded stride 9
    __shared__ float dvs[32];
    int row0 = blockIdx.x * 32;
    int tid = threadIdx.x;
    int node_l = tid >> 3, j3 = tid & 7;
    int node = row0 + node_l;
    H8 acc0, acc1, acc2, acc3;
    acc0.f = make_float4(0.f, 0.f, 0.f, 0.f);
    acc1.f = acc0.f; acc2.f = acc0.f; acc3.f = acc0.f;
    __half2 dh = __float2half2_rn(0.f);
    if (node < N) {
        float2 sxd = xd[node];
        float di = sxd.x;
        if (j3 == 0) dvs[node_l] = di;
        dh = __float2half2_rn(di);
        H8 tv; tv.f = th4[(size_t)__float_as_int(sxd.y) * 8 + j3];
        acc0.h[0] = __hmul2(dh, tv.h[0]); acc0.h[1] = __hmul2(dh, tv.h[1]);
        acc0.h[2] = __hmul2(dh, tv.h[2]); acc0.h[3] = __hmul2(dh, tv.h[3]);
        int2 ri = rowinfo[node];
        const int4* cs = (const int4*)(csr_src + ri.x);
        int nq = ri.y >> 2;
        int q = 0;
        for (; q + 1 < nq; q += 2) {
            int4 sA = cs[q], sB = cs[q + 1];
            unsigned a0 = (unsigned)sA.x, a1 = (unsigned)sA.y;
            unsigned a2 = (unsigned)sA.z, a3 = (unsigned)sA.w;
            unsigned b0i = (unsigned)sB.x, b1i = (unsigned)sB.y;
            unsigned b2i = (unsigned)sB.z, b3i = (unsigned)sB.w;
            H8 u0, u1, u2, u3, u4, u5, u6, u7;
            u0.f = th4[(size_t)(a0 >> 18) * 8 + j3];
            u1.f = th4[(size_t)(a1 >> 18) * 8 + j3];
            u2.f = th4[(size_t)(a2 >> 18) * 8 + j3];
            u3.f = th4[(size_t)(a3 >> 18) * 8 + j3];
            u4.f = th4[(size_t)(b0i >> 18) * 8 + j3];
            u5.f = th4[(size_t)(b1i >> 18) * 8 + j3];
            u6.f = th4[(size_t)(b2i >> 18) * 8 + j3];
            u7.f = th4[(size_t)(b3i >> 18) * 8 + j3];
            __half2 w0 = __half2half2(dinvh[a0 & SRCMASK]);
            __half2 w1 = __half2half2(dinvh[a1 & SRCMASK]);
            __half2 w2 = __half2half2(dinvh[a2 & SRCMASK]);
            __half2 w3 = __half2half2(dinvh[a3 & SRCMASK]);
            __half2 w4 = __half2half2(dinvh[b0i & SRCMASK]);
            __half2 w5 = __half2half2(dinvh[b1i & SRCMASK]);
            __half2 w6 = __half2half2(dinvh[b2i & SRCMASK]);
            __half2 w7 = __half2half2(dinvh[b3i & SRCMASK]);
            #pragma unroll
            for (int t = 0; t < 4; ++t) {
                acc0.h[t] = __hfma2(w0, u0.h[t], acc0.h[t]);
                acc1.h[t] = __hfma2(w1, u1.h[t], acc1.h[t]);
                acc2.h[t] = __hfma2(w2, u2.h[t], acc2.h[t]);
                acc3.h[t] = __hfma2(w3, u3.h[t], acc3.h[t]);
                acc0.h[t] = __hfma2(w4, u4.h[t], acc0.h[t]);
                acc1.h[t] = __hfma2(w5, u5.h[t], acc1.h[t]);
                acc2.h[t] = __hfma2(w6, u6.h[t], acc2.h[t]);
                acc3.h[t] = __hfma2(w7, u7.h[t], acc3.h[t]);
            }
        }
        if (q < nq) {
            int4 sA = cs[q];
            unsigned a0 = (unsigned)sA.x, a1 = (unsigned)sA.y;
            unsigned a2 = (unsigned)sA.z, a3 = (unsigned)sA.w;
            H8 u0, u1, u2, u3;
            u0.f = th4[(size_t)(a0 >> 18) * 8 + j3];
            u1.f = th4[(size_t)(a1 >> 18) * 8 + j3];
            u2.f = th4[(size_t)(a2 >> 18) * 8 + j3];
            u3.f = th4[(size_t)(a3 >> 18) * 8 + j3];
            __half2 w0 = __half2half2(dinvh[a0 & SRCMASK]);
            __half2 w1 = __half2half2(dinvh[a1 & SRCMASK]);
            __half2 w2 = __half2half2(dinvh[a2 & SRCMASK]);
            __half2 w3 = __half2half2(dinvh[a3 & SRCMASK]);
            #pragma unroll
            for (int t = 0; t < 4; ++t) {
                acc0.h[t] = __hfma2(w0, u0.h[t], acc0.h[t]);
                acc1.h[t] = __hfma2(w1, u1.h[t], acc1.h[t]);
                acc2.h[t] = __hfma2(w2, u2.h[t], acc2.h[t]);
                acc3.h[t] = __hfma2(w3, u3.h[t], acc3.h[t]);
            }
        }
        #pragma unroll
        for (int t = 0; t < 4; ++t)
            acc0.h[t] = __hmul2(dh, __hadd2(__hadd2(acc0.h[t], acc1.h[t]),
                                            __hadd2(acc2.h[t], acc3.h[t])));
    }
    Hs4[node_l * 9 + j3] = acc0.f;
    __syncthreads();

    // MFMA MLP: 2 tiles of 16 rows; each wave does cols wave*16..+15, K=64.
    int wave = tid >> 6, lane = tid & 63;
    int m = lane & 15, quad = lane >> 4;
    int ncol = wave * 16 + m;
    F4H8 b0, b1;
    const float4* WT4 = (const float4*)wt;
    b0.f = WT4[ncol * 8 + quad];
    b1.f = WT4[ncol * 8 + 4 + quad];
    float bb_ = bias[ncol];
    #pragma unroll
    for (int t = 0; t < 2; ++t) {
        F4H8 a0, a1;
        a0.f = Hs4[(t * 16 + m) * 9 + quad];
        a1.f = Hs4[(t * 16 + m) * 9 + 4 + quad];
        float4_t acc = {0.f, 0.f, 0.f, 0.f};
        acc = __builtin_amdgcn_mfma_f32_16x16x32_f16(a0.h, b0.h, acc, 0, 0, 0);
        acc = __builtin_amdgcn_mfma_f32_16x16x32_f16(a1.h, b1.h, acc, 0, 0, 0);
        #pragma unroll
        for (int reg = 0; reg < 4; ++reg) {
            int row = t * 16 + quad * 4 + reg;
            int grow = row0 + row;
            if (grow < N) {
                float h = fmaxf(acc[reg] + bb_, 0.0f);
                g1h[(size_t)grow * DD + ncol] = __float2half(dvs[row] * h);
            }
        }
    }
}

// -------- layer 2 + pool: gather g1h, MFMA MLP, Wlin dot + segmented pool ---
__global__ __launch_bounds__(256, 8) void layer2_pool_kernel(
        const int2* __restrict__ rowinfo,
        const int* __restrict__ csr_src, const float2* __restrict__ xd,
        const float4* __restrict__ g1h4, const __half* __restrict__ wt,
        const float* __restrict__ bias, const int* __restrict__ batch,
        const float* __restrict__ Wlin, float* __restrict__ outacc, int N) {
    __shared__ float4 Hs4[32 * 9];       // padded stride 9
    __shared__ float lp0[128], lp1[128]; // [wave][row]
    __shared__ float p0s[32], p1s[32];
    __shared__ int   bat[32];
    int row0 = blockIdx.x * 32;
    int tid = threadIdx.x;
    int node_l = tid >> 3, j3 = tid & 7;
    int node = row0 + node_l;
    H8 acc0, acc1, acc2, acc3;
    acc0.f = make_float4(0.f, 0.f, 0.f, 0.f);
    acc1.f = acc0.f; acc2.f = acc0.f; acc3.f = acc0.f;
    if (node < N) {
        float di = xd[node].x;
        acc0.f = g1h4[(size_t)node * 8 + j3];   // self term, weight 1
        int2 ri = rowinfo[node];
        const int4* cs = (const int4*)(csr_src + ri.x);
        int nq = ri.y >> 2;
        int q = 0;
        for (; q + 1 < nq; q += 2) {
            int4 sA = cs[q], sB = cs[q + 1];
            H8 u0, u1, u2, u3, u4, u5, u6, u7;
            u0.f = g1h4[(size_t)(sA.x & SRCMASK) * 8 + j3];
            u1.f = g1h4[(size_t)(sA.y & SRCMASK) * 8 + j3];
            u2.f = g1h4[(size_t)(sA.z & SRCMASK) * 8 + j3];
            u3.f = g1h4[(size_t)(sA.w & SRCMASK) * 8 + j3];
            u4.f = g1h4[(size_t)(sB.x & SRCMASK) * 8 + j3];
            u5.f = g1h4[(size_t)(sB.y & SRCMASK) * 8 + j3];
            u6.f = g1h4[(size_t)(sB.z & SRCMASK) * 8 + j3];
            u7.f = g1h4[(size_t)(sB.w & SRCMASK) * 8 + j3];
            #pragma unroll
            for (int t = 0; t < 4; ++t) {
                acc0.h[t] = __hadd2(acc0.h[t], u0.h[t]);
                acc1.h[t] = __hadd2(acc1.h[t], u1.h[t]);
                acc2.h[t] = __hadd2(acc2.h[t], u2.h[t]);
                acc3.h[t] = __hadd2(acc3.h[t], u3.h[t]);
                acc0.h[t] = __hadd2(acc0.h[t], u4.h[t]);
                acc1.h[t] = __hadd2(acc1.h[t], u5.h[t]);
                acc2.h[t] = __hadd2(acc2.h[t], u6.h[t]);
                acc3.h[t] = __hadd2(acc3.h[t], u7.h[t]);
            }
        }
        if (q < nq) {
            int4 sA = cs[q];
            H8 u0, u1, u2, u3;
            u0.f = g1h4[(size_t)(sA.x & SRCMASK) * 8 + j3];
            u1.f = g1h4[(size_t)(sA.y & SRCMASK) * 8 + j3];
            u2.f = g1h4[(size_t)(sA.z & SRCMASK) * 8 + j3];
            u3.f = g1h4[(size_t)(sA.w & SRCMASK) * 8 + j3];
            #pragma unroll
            for (int t = 0; t < 4; ++t) {
                acc0.h[t] = __hadd2(acc0.h[t], u0.h[t]);
                acc1.h[t] = __hadd2(acc1.h[t], u1.h[t]);
                acc2.h[t] = __hadd2(acc2.h[t], u2.h[t]);
                acc3.h[t] = __hadd2(acc3.h[t], u3.h[t]);
            }
        }
        __half2 dih = __float2half2_rn(di);
        #pragma unroll
        for (int t = 0; t < 4; ++t)
            acc0.h[t] = __hmul2(dih, __hadd2(__hadd2(acc0.h[t], acc1.h[t]),
                                             __hadd2(acc2.h[t], acc3.h[t])));
    }
    Hs4[node_l * 9 + j3] = acc0.f;
    __syncthreads();

    int wave = tid >> 6, lane = tid & 63;
    int m = lane & 15, quad = lane >> 4;
    int ncol = wave * 16 + m;
    F4H8 b0, b1;
    const float4* WT4 = (const float4*)wt;
    b0.f = WT4[ncol * 8 + quad];
    b1.f = WT4[ncol * 8 + 4 + quad];
    float bb_  = bias[ncol];
    float wl0 = Wlin[ncol * 2 + 0];
    float wl1 = Wlin[ncol * 2 + 1];
    #pragma unroll
    for (int t = 0; t < 2; ++t) {
        F4H8 a0, a1;
        a0.f = Hs4[(t * 16 + m) * 9 + quad];
        a1.f = Hs4[(t * 16 + m) * 9 + 4 + quad];
        float4_t acc = {0.f, 0.f, 0.f, 0.f};
        acc = __builtin_amdgcn_mfma_f32_16x16x32_f16(a0.h, b0.h, acc, 0, 0, 0);
        acc = __builtin_amdgcn_mfma_f32_16x16x32_f16(a1.h, b1.h, acc, 0, 0, 0);
        #pragma unroll
        for (int reg = 0; reg < 4; ++reg) {
            int row = t * 16 + quad * 4 + reg;
            int grow = row0 + row;
            float h = (grow < N) ? fmaxf(acc[reg] + bb_, 0.0f) : 0.0f;
            float p0 = h * wl0;
            float p1 = h * wl1;
            #pragma unroll
            for (int off = 8; off >= 1; off >>= 1) {   // sum over 16 cols (m)
                p0 += __shfl_xor(p0, off);
                p1 += __shfl_xor(p1, off);
            }
            if (m == 0) {
                lp0[wave * 32 + row] = p0;
                lp1[wave * 32 + row] = p1;
            }
        }
    }
    __syncthreads();
    if (tid < 32) {
        int grow = row0 + tid;
        p0s[tid] = lp0[tid] + lp0[32 + tid] + lp0[64 + tid] + lp0[96 + tid];
        p1s[tid] = lp1[tid] + lp1[32 + tid] + lp1[64 + tid] + lp1[96 + tid];
        bat[tid] = (grow < N) ? batch[grow] : -1;
    }
    __syncthreads();
    if (tid < 32) {
        int bg = bat[tid];
        bool head = (bg >= 0) && (tid == 0 || bat[tid - 1] != bg);
        if (head) {
            float s0 = 0.f, s1 = 0.f;
            for (int k = tid; k < 32 && bat[k] == bg; ++k) {
                s0 += p0s[k];
                s1 += p1s[k];
            }
            atomAddF(&outacc[bg * 2 + 0], s0);
            atomAddF(&outacc[bg * 2 + 1], s1);
        }
    }
}

// counts via binary search on sorted batch; then divide + blin
__global__ void final_kernel(const float* __restrict__ outacc,
                             const int* __restrict__ batch,
                             const float* __restrict__ blin,
                             float* __restrict__ out, int G, int N) {
    int t = blockIdx.x * blockDim.x + threadIdx.x;
    if (t >= G * 2) return;
    int g = t >> 1, c = t & 1;
    int lo = 0, hi = N;
    while (lo < hi) { int m = (lo + hi) >> 1; if (batch[m] < g) lo = m + 1; else hi = m; }
    int lo2 = lo, hi2 = N;
    while (lo2 < hi2) { int m = (lo2 + hi2) >> 1; if (batch[m] < g + 1) lo2 = m + 1; else hi2 = m; }
    float cnt = (float)(lo2 - lo);
    out[t] = outacc[t] / fmaxf(cnt, 1.0f) + blin[c];
}

extern "C" void kernel_launch(void* const* d_in, const int* in_sizes, int n_in,
                              void* d_out, int out_size, void* d_ws, size_t ws_size,
                              hipStream_t stream) {
    const int*   x      = (const int*)d_in[0];
    const int*   ei     = (const int*)d_in[1];   // [2,E] row-major
    const int*   batch  = (const int*)d_in[3];
    const float* table  = (const float*)d_in[4];
    const float* W1     = (const float*)d_in[5];
    const float* b1     = (const float*)d_in[6];
    const float* W2     = (const float*)d_in[7];
    const float* b2     = (const float*)d_in[8];
    const float* Wlin   = (const float*)d_in[9];
    const float* blin   = (const float*)d_in[10];
    float* out = (float*)d_out;

    const int N = in_sizes[0];
    const int E = in_sizes[2];          // edge_type count == E
    const int G = out_size / 2;
    const int TBL = in_sizes[4];        // VOCAB*DD floats

    const int* src = ei;
    const int* dst = ei + E;

    const int KB = (N + 255) / 256;     // scan blocks (node granularity)
    const int CSRSZ = ((E + 3 * N + 64) + 1) & ~1;   // worst-case padded slots

    // workspace layout (keep 16-B alignment for b128 reads)
    __half* g1h     = (__half*)d_ws;                      // (N+1)*64 halves
    __half* th      = g1h + (size_t)(N + 1) * DD;         // TBL halves
    __half* w1t     = th + TBL;                           // 4096 halves
    __half* w2t     = w1t + DD * DD;                      // 4096 halves
    int*    csr_src = (int*)(w2t + DD * DD);              // CSRSZ ints
    int2*   rowinfo = (int2*)(csr_src + CSRSZ);           // N int2
    float2* xd      = (float2*)(rowinfo + N);             // N+1 float2
    __half* dinvh   = (__half*)(xd + N + 1);              // N+1 halves (pad even)
    int*    deg     = (int*)(dinvh + (size_t)((N + 2) & ~1)); // N ints
    int*    cursor  = deg + N;                            // N ints
    int*    bsum    = cursor + N;                         // KB+1
    int*    bbase   = bsum + KB + 1;                      // KB+1
    float*  outacc  = (float*)(bbase + KB + 1);           // 2G

    const int BT = 256;
    const int GSTRIDE = 2048;           // grid for edge-stride passes

    // partition: zero -> count -> blocksum -> scan -> rowbase -> place
    int zb = (max(N, 2 * G) + BT - 1) / BT;
    zero_kernel<<<zb, BT, 0, stream>>>(deg, outacc, N, 2 * G);
    count_kernel<<<GSTRIDE, BT, 0, stream>>>(dst, E, deg,
                                             (const float2*)table,
                                             (__half2*)th, TBL / 2,
                                             W1, W2, w1t, w2t);
    blocksum_kernel<<<KB, BT, 0, stream>>>(deg, bsum, N);
    scan_kernel<<<1, BT, 0, stream>>>(bsum, bbase, KB);
    rowbase_kernel<<<KB, BT, 0, stream>>>(deg, bbase, x, rowinfo, xd, dinvh,
                                          cursor, csr_src, g1h, N);
    place_kernel<<<GSTRIDE, BT, 0, stream>>>(src, dst, E, x, cursor, csr_src);

    // layer 1 (embed+agg+MFMA-MLP+relu fused; writes g1h = fp16(dinv*h1))
    int gRow = (N + 31) / 32;
    layer1_kernel<<<gRow, BT, 0, stream>>>(rowinfo, csr_src, xd, dinvh,
                                           (const float4*)th, w1t, b1, g1h, N);
    // layer 2 (agg+MFMA-MLP+relu+pool fused)
    layer2_pool_kernel<<<gRow, BT, 0, stream>>>(rowinfo, csr_src, xd,
                                                (const float4*)g1h, w2t, b2,
                                                batch, Wlin, outacc, N);
    // final
    final_kernel<<<(G * 2 + BT - 1) / BT, BT, 0, stream>>>(outacc, batch, blin,
                                                           out, G, N);
}

// Round 3
// 218.170 us; speedup vs baseline: 1.6628x; 1.6628x over previous
//
#include <hip/hip_runtime.h>
#include <hip/hip_fp16.h>

// ---------------------------------------------------------------------------
// GCN forward on MI355X — round 21.
//  * R20 post-mortem: direct per-node-cursor placement wrote 107 MB to HBM
//    for 6.4 MB of CSR payload (17x line-amplification on random 4B scatters
//    into a 25 MB region) -> 120 us.  The bucketed two-stage scheme's value
//    is WRITE LOCALITY, not cursor bookkeeping.  Reverted to the R19
//    partition (bin_count -> totals -> scan_bb -> scanB -> fill -> build_csr).
//  * One improvement kept: build_csr now stages its bucket's pairbuf slice
//    (Poisson lambda=2048, max ~2.3k over 782 buckets) into a 4096-entry LDS
//    buffer ONCE and runs both the count pass and the place pass from LDS
//    (global two-pass fallback if a slice exceeds the cap).  Removes one
//    full 6.4 MB global stream from the partition.
//  * Layers unchanged (R19 packed CSR: entry = src | x[src]<<18).
// ---------------------------------------------------------------------------

#define DD 64          // feature dim
#define BKT 256        // nodes per bucket (CSR build)
#define MAXK 1024      // max buckets; hist/cur row stride
#define NBLK 256       // partition blocks (chunks)
#define SLACK 772      // per-bucket csr slack: 3*256 pad + 4 alignment
#define BTE 1024       // threads/block for per-edge passes
#define SRCMASK 0x3FFFF  // low 18 bits = src node id
#define PBUF_CAP 4096  // LDS staging capacity for one bucket's pair slice

typedef _Float16 half8_t __attribute__((ext_vector_type(8)));
typedef float float4_t __attribute__((ext_vector_type(4)));
union F4H8 { float4 f; half8_t h; };
union H8   { float4 f; __half2 h[4]; };

static __device__ __forceinline__ void atomAddF(float* p, float v) {
    unsafeAtomicAdd(p, v);   // global_atomic_add_f32 on gfx950
}

// ---- pass A: per-chunk histogram (+ fp16 conversions piggy-backed) --------
__global__ __launch_bounds__(BTE) void bin_count_kernel(
        const int* __restrict__ dst, int E, int CH,
        int* __restrict__ hist, int K,
        const float2* __restrict__ table2, __half2* __restrict__ th2, int n2,
        const float* __restrict__ W1, const float* __restrict__ W2,
        __half* __restrict__ w1t, __half* __restrict__ w2t) {
    __shared__ int lh[MAXK];
    int tid = threadIdx.x;
    for (int i = tid; i < K; i += BTE) lh[i] = 0;
    __syncthreads();
    int stride = gridDim.x * BTE;
    for (int i = blockIdx.x * BTE + tid; i < n2; i += stride)
        th2[i] = __float22half2_rn(table2[i]);
    for (int i = blockIdx.x * BTE + tid; i < DD * DD; i += stride) {
        int n = i >> 6, k = i & 63;
        w1t[i] = __float2half(W1[k * DD + n]);   // WT[n][k]
        w2t[i] = __float2half(W2[k * DD + n]);
    }
    int e0 = blockIdx.x * CH;
    int e1 = min(E, e0 + CH);
    for (int e = e0 + tid; e < e1; e += BTE)
        atomicAdd(&lh[((unsigned)dst[e]) >> 8], 1);
    __syncthreads();
    for (int b = tid; b < K; b += BTE)
        hist[blockIdx.x * MAXK + b] = lh[b];     // coalesced private row
}

// ---- pass B0: bucket totals, one WAVE per bucket; zero outacc -------------
__global__ __launch_bounds__(256) void totals_kernel(
        const int* __restrict__ hist, int* __restrict__ bts,
        float* __restrict__ outacc, int K, int G2) {
    int gt = blockIdx.x * 256 + threadIdx.x;
    if (gt < G2) outacc[gt] = 0.f;
    int wid = gt >> 6;            // wave id = bucket
    int lane = threadIdx.x & 63;
    if (wid >= K) return;
    const int PER = NBLK / 64;    // 4 cells per lane
    int s = 0;
    #pragma unroll
    for (int i = 0; i < PER; ++i)
        s += hist[(lane * PER + i) * MAXK + wid];
    #pragma unroll
    for (int off = 32; off >= 1; off >>= 1)
        s += __shfl_xor(s, off);
    if (lane == 0) bts[wid] = s;
}

// ---- pass B1: exclusive scan of bts[K] -> bb; bb[K] = E -------------------
__global__ __launch_bounds__(256) void scan_bb_kernel(
        const int* __restrict__ bts, int* __restrict__ bb, int K, int E) {
    __shared__ int part[256];
    int tid = threadIdx.x;
    int CH2 = (K + 255) / 256;
    int base = tid * CH2;
    int s = 0;
    for (int i = 0; i < CH2; ++i) {
        int idx = base + i;
        if (idx < K) s += bts[idx];
    }
    part[tid] = s;
    __syncthreads();
    if (tid < 64) {
        int carry = 0;
        for (int c = 0; c < 4; ++c) {
            int orig = part[c * 64 + tid];
            int v = orig;
            #pragma unroll
            for (int off = 1; off < 64; off <<= 1) {
                int t = __shfl_up(v, off);
                if (tid >= off) v += t;
            }
            int tot = __shfl(v, 63);
            part[c * 64 + tid] = v - orig + carry;   // exclusive
            carry += tot;
        }
    }
    __syncthreads();
    int run = part[tid];
    for (int i = 0; i < CH2; ++i) {
        int idx = base + i;
        if (idx < K) {
            bb[idx] = run;
            run += bts[idx];
        }
    }
    if (tid == 0) bb[K] = E;
}

// ---- pass B2: one WAVE per bucket scans across blocks -> cur[blk][bucket] -
__global__ __launch_bounds__(256) void scanB_kernel(
        const int* __restrict__ hist, const int* __restrict__ bb,
        int* __restrict__ cur, int K) {
    int wid = (blockIdx.x * 256 + threadIdx.x) >> 6;   // global wave id = bucket
    int lane = threadIdx.x & 63;
    if (wid >= K) return;
    int b = wid;
    const int PER = NBLK / 64;    // 4 blocks per lane
    int v[PER];
    int sum = 0;
    #pragma unroll
    for (int i = 0; i < PER; ++i) {
        v[i] = hist[(lane * PER + i) * MAXK + b];
        sum += v[i];
    }
    int pref = sum;
    #pragma unroll
    for (int off = 1; off < 64; off <<= 1) {
        int t = __shfl_up(pref, off);
        if (lane >= off) pref += t;
    }
    int run = bb[b] + pref - sum;   // exclusive
    #pragma unroll
    for (int i = 0; i < PER; ++i) {
        cur[(lane * PER + i) * MAXK + b] = run;
        run += v[i];
    }
}

// ---- pass C: append packed pairs; cursors in LDS (block-private cells) ----
__global__ __launch_bounds__(BTE) void fill_kernel(
        const int* __restrict__ src, const int* __restrict__ dst, int E, int CH,
        const int* __restrict__ cur, int* __restrict__ pairbuf, int K) {
    __shared__ int lcur[MAXK];
    int tid = threadIdx.x;
    for (int b = tid; b < K; b += BTE)
        lcur[b] = cur[blockIdx.x * MAXK + b];
    __syncthreads();
    int e0 = blockIdx.x * CH;
    int e1 = min(E, e0 + CH);
    for (int e = e0 + tid; e < e1; e += BTE) {
        int s = src[e], d = dst[e];
        int pos = atomicAdd(&lcur[((unsigned)d) >> 8], 1);
        pairbuf[pos] = s | ((d & 255) << 24);
    }
}

// ---- pass D: per-bucket padded CSR build + rowinfo/xd/dinvh (coalesced) ---
// csr entry = src | (x[src] << 18): layer1 decodes the embedding row directly,
// layer2 masks with SRCMASK.  Sentinel pad = N (x-part 0 -> zeroed th row 0,
// dinvh[N] = 0 -> zero weight, g1h row N zeroed -> zero layer2 term).
// Bucket's pairbuf slice staged ONCE into LDS; both passes read from LDS.
__global__ __launch_bounds__(256) void build_csr_kernel(
        const int* __restrict__ pairbuf, const int* __restrict__ bnd,
        const int* __restrict__ x, int2* __restrict__ rowinfo,
        float2* __restrict__ xd, __half* __restrict__ dinvh,
        int* __restrict__ csr_src, __half* __restrict__ g1h, int N) {
    __shared__ int cnt[256], basel[256], curl[256];
    __shared__ int pbuf[PBUF_CAP];
    int tid = threadIdx.x;
    int b = blockIdx.x;
    int node0 = b << 8;
    cnt[tid] = 0;
    __syncthreads();
    int bb0 = bnd[b], bb1 = bnd[b + 1];
    int L = bb1 - bb0;
    bool fits = (L <= PBUF_CAP);
    if (fits) {
        for (int i = tid; i < L; i += 256) {
            int pk = pairbuf[bb0 + i];
            pbuf[i] = pk;
            atomicAdd(&cnt[((unsigned)pk) >> 24], 1);
        }
    } else {
        for (int i = bb0 + tid; i < bb1; i += 256)
            atomicAdd(&cnt[((unsigned)pairbuf[i]) >> 24], 1);
    }
    __syncthreads();
    int c  = cnt[tid];
    int pc = (c + 3) & ~3;              // padded count
    {
        __syncthreads();
        basel[tid] = pc;
        __syncthreads();
        if (tid < 64) {
            int carry = 0;
            for (int cc = 0; cc < 4; ++cc) {
                int orig = basel[cc * 64 + tid];
                int v = orig;
                #pragma unroll
                for (int off = 1; off < 64; off <<= 1) {
                    int t = __shfl_up(v, off);
                    if (tid >= off) v += t;
                }
                int tot = __shfl(v, 63);
                cnt[cc * 64 + tid] = v - orig + carry;   // exclusive
                carry += tot;
            }
        }
        __syncthreads();
    }
    int cb0 = ((bb0 + 3) & ~3) + SLACK * b;   // aligned csr base for bucket
    int node = node0 + tid;
    int myBase = cb0 + cnt[tid];
    curl[tid] = myBase;
    if (node < N) {
        rowinfo[node] = make_int2(myBase, pc);
        float di = rsqrtf((float)c + 1.0f);
        xd[node] = make_float2(di, __int_as_float(x[node]));
        dinvh[node] = __float2half(di);
        for (int t = c; t < pc; ++t) csr_src[myBase + t] = N;   // sentinel pad
    } else if (node == N) {
        xd[N] = make_float2(0.0f, __int_as_float(0));           // zero weight
        dinvh[N] = __float2half(0.0f);
        float2* z = (float2*)(g1h + (size_t)N * DD);            // zero row N
        for (int t = 0; t < DD / 4; ++t) z[t] = make_float2(0.f, 0.f);
    }
    __syncthreads();
    if (fits) {
        for (int i = tid; i < L; i += 256) {
            int pk = pbuf[i];
            int pos = atomicAdd(&curl[((unsigned)pk) >> 24], 1);
            int s = pk & 0x00FFFFFF;
            csr_src[pos] = (int)(((unsigned)s) | (((unsigned)x[s]) << 18));
        }
    } else {
        for (int i = bb0 + tid; i < bb1; i += 256) {
            int pk = pairbuf[i];
            int pos = atomicAdd(&curl[((unsigned)pk) >> 24], 1);
            int s = pk & 0x00FFFFFF;
            csr_src[pos] = (int)(((unsigned)s) | (((unsigned)x[s]) << 18));
        }
    }
}

// ---------------- layer 1: agg from fp16 table, MFMA MLP, g1h = f16(dv*h1) --
// 8 lanes/node, b128 chunks; unroll x2; Hs stride 9 (bank-conflict pad).
// Packed-CSR decode: th row = entry >> 18, weight = dinvh[entry & SRCMASK]
// (independent 2B load, issues concurrently with the 16B th4 gather).
__global__ __launch_bounds__(256, 8) void layer1_kernel(
        const int2* __restrict__ rowinfo,
        const int* __restrict__ csr_src, const float2* __restrict__ xd,
        const __half* __restrict__ dinvh,
        const float4* __restrict__ th4, const __half* __restrict__ wt,
        const float* __restrict__ bias, __half* __restrict__ g1h, int N) {
    __shared__ float4 Hs4[32 * 9];   // padded stride 9
    __shared__ float dvs[32];
    int row0 = blockIdx.x * 32;
    int tid = threadIdx.x;
    int node_l = tid >> 3, j3 = tid & 7;
    int node = row0 + node_l;
    H8 acc0, acc1, acc2, acc3;
    acc0.f = make_float4(0.f, 0.f, 0.f, 0.f);
    acc1.f = acc0.f; acc2.f = acc0.f; acc3.f = acc0.f;
    __half2 dh = __float2half2_rn(0.f);
    if (node < N) {
        float2 sxd = xd[node];
        float di = sxd.x;
        if (j3 == 0) dvs[node_l] = di;
        dh = __float2half2_rn(di);
        H8 tv; tv.f = th4[(size_t)__float_as_int(sxd.y) * 8 + j3];
        acc0.h[0] = __hmul2(dh, tv.h[0]); acc0.h[1] = __hmul2(dh, tv.h[1]);
        acc0.h[2] = __hmul2(dh, tv.h[2]); acc0.h[3] = __hmul2(dh, tv.h[3]);
        int2 ri = rowinfo[node];
        const int4* cs = (const int4*)(csr_src + ri.x);
        int nq = ri.y >> 2;
        int q = 0;
        for (; q + 1 < nq; q += 2) {
            int4 sA = cs[q], sB = cs[q + 1];
            unsigned a0 = (unsigned)sA.x, a1 = (unsigned)sA.y;
            unsigned a2 = (unsigned)sA.z, a3 = (unsigned)sA.w;
            unsigned b0i = (unsigned)sB.x, b1i = (unsigned)sB.y;
            unsigned b2i = (unsigned)sB.z, b3i = (unsigned)sB.w;
            H8 u0, u1, u2, u3, u4, u5, u6, u7;
            u0.f = th4[(size_t)(a0 >> 18) * 8 + j3];
            u1.f = th4[(size_t)(a1 >> 18) * 8 + j3];
            u2.f = th4[(size_t)(a2 >> 18) * 8 + j3];
            u3.f = th4[(size_t)(a3 >> 18) * 8 + j3];
            u4.f = th4[(size_t)(b0i >> 18) * 8 + j3];
            u5.f = th4[(size_t)(b1i >> 18) * 8 + j3];
            u6.f = th4[(size_t)(b2i >> 18) * 8 + j3];
            u7.f = th4[(size_t)(b3i >> 18) * 8 + j3];
            __half2 w0 = __half2half2(dinvh[a0 & SRCMASK]);
            __half2 w1 = __half2half2(dinvh[a1 & SRCMASK]);
            __half2 w2 = __half2half2(dinvh[a2 & SRCMASK]);
            __half2 w3 = __half2half2(dinvh[a3 & SRCMASK]);
            __half2 w4 = __half2half2(dinvh[b0i & SRCMASK]);
            __half2 w5 = __half2half2(dinvh[b1i & SRCMASK]);
            __half2 w6 = __half2half2(dinvh[b2i & SRCMASK]);
            __half2 w7 = __half2half2(dinvh[b3i & SRCMASK]);
            #pragma unroll
            for (int t = 0; t < 4; ++t) {
                acc0.h[t] = __hfma2(w0, u0.h[t], acc0.h[t]);
                acc1.h[t] = __hfma2(w1, u1.h[t], acc1.h[t]);
                acc2.h[t] = __hfma2(w2, u2.h[t], acc2.h[t]);
                acc3.h[t] = __hfma2(w3, u3.h[t], acc3.h[t]);
                acc0.h[t] = __hfma2(w4, u4.h[t], acc0.h[t]);
                acc1.h[t] = __hfma2(w5, u5.h[t], acc1.h[t]);
                acc2.h[t] = __hfma2(w6, u6.h[t], acc2.h[t]);
                acc3.h[t] = __hfma2(w7, u7.h[t], acc3.h[t]);
            }
        }
        if (q < nq) {
            int4 sA = cs[q];
            unsigned a0 = (unsigned)sA.x, a1 = (unsigned)sA.y;
            unsigned a2 = (unsigned)sA.z, a3 = (unsigned)sA.w;
            H8 u0, u1, u2, u3;
            u0.f = th4[(size_t)(a0 >> 18) * 8 + j3];
            u1.f = th4[(size_t)(a1 >> 18) * 8 + j3];
            u2.f = th4[(size_t)(a2 >> 18) * 8 + j3];
            u3.f = th4[(size_t)(a3 >> 18) * 8 + j3];
            __half2 w0 = __half2half2(dinvh[a0 & SRCMASK]);
            __half2 w1 = __half2half2(dinvh[a1 & SRCMASK]);
            __half2 w2 = __half2half2(dinvh[a2 & SRCMASK]);
            __half2 w3 = __half2half2(dinvh[a3 & SRCMASK]);
            #pragma unroll
            for (int t = 0; t < 4; ++t) {
                acc0.h[t] = __hfma2(w0, u0.h[t], acc0.h[t]);
                acc1.h[t] = __hfma2(w1, u1.h[t], acc1.h[t]);
                acc2.h[t] = __hfma2(w2, u2.h[t], acc2.h[t]);
                acc3.h[t] = __hfma2(w3, u3.h[t], acc3.h[t]);
            }
        }
        #pragma unroll
        for (int t = 0; t < 4; ++t)
            acc0.h[t] = __hmul2(dh, __hadd2(__hadd2(acc0.h[t], acc1.h[t]),
                                            __hadd2(acc2.h[t], acc3.h[t])));
    }
    Hs4[node_l * 9 + j3] = acc0.f;
    __syncthreads();

    // MFMA MLP: 2 tiles of 16 rows; each wave does cols wave*16..+15, K=64.
    int wave = tid >> 6, lane = tid & 63;
    int m = lane & 15, quad = lane >> 4;
    int ncol = wave * 16 + m;
    F4H8 b0, b1;
    const float4* WT4 = (const float4*)wt;
    b0.f = WT4[ncol * 8 + quad];
    b1.f = WT4[ncol * 8 + 4 + quad];
    float bb_ = bias[ncol];
    #pragma unroll
    for (int t = 0; t < 2; ++t) {
        F4H8 a0, a1;
        a0.f = Hs4[(t * 16 + m) * 9 + quad];
        a1.f = Hs4[(t * 16 + m) * 9 + 4 + quad];
        float4_t acc = {0.f, 0.f, 0.f, 0.f};
        acc = __builtin_amdgcn_mfma_f32_16x16x32_f16(a0.h, b0.h, acc, 0, 0, 0);
        acc = __builtin_amdgcn_mfma_f32_16x16x32_f16(a1.h, b1.h, acc, 0, 0, 0);
        #pragma unroll
        for (int reg = 0; reg < 4; ++reg) {
            int row = t * 16 + quad * 4 + reg;
            int grow = row0 + row;
            if (grow < N) {
                float h = fmaxf(acc[reg] + bb_, 0.0f);
                g1h[(size_t)grow * DD + ncol] = __float2half(dvs[row] * h);
            }
        }
    }
}

// -------- layer 2 + pool: gather g1h, MFMA MLP, Wlin dot + segmented pool ---
__global__ __launch_bounds__(256, 8) void layer2_pool_kernel(
        const int2* __restrict__ rowinfo,
        const int* __restrict__ csr_src, const float2* __restrict__ xd,
        const float4* __restrict__ g1h4, const __half* __restrict__ wt,
        const float* __restrict__ bias, const int* __restrict__ batch,
        const float* __restrict__ Wlin, float* __restrict__ outacc, int N) {
    __shared__ float4 Hs4[32 * 9];       // padded stride 9
    __shared__ float lp0[128], lp1[128]; // [wave][row]
    __shared__ float p0s[32], p1s[32];
    __shared__ int   bat[32];
    int row0 = blockIdx.x * 32;
    int tid = threadIdx.x;
    int node_l = tid >> 3, j3 = tid & 7;
    int node = row0 + node_l;
    H8 acc0, acc1, acc2, acc3;
    acc0.f = make_float4(0.f, 0.f, 0.f, 0.f);
    acc1.f = acc0.f; acc2.f = acc0.f; acc3.f = acc0.f;
    if (node < N) {
        float di = xd[node].x;
        acc0.f = g1h4[(size_t)node * 8 + j3];   // self term, weight 1
        int2 ri = rowinfo[node];
        const int4* cs = (const int4*)(csr_src + ri.x);
        int nq = ri.y >> 2;
        int q = 0;
        for (; q + 1 < nq; q += 2) {
            int4 sA = cs[q], sB = cs[q + 1];
            H8 u0, u1, u2, u3, u4, u5, u6, u7;
            u0.f = g1h4[(size_t)(sA.x & SRCMASK) * 8 + j3];
            u1.f = g1h4[(size_t)(sA.y & SRCMASK) * 8 + j3];
            u2.f = g1h4[(size_t)(sA.z & SRCMASK) * 8 + j3];
            u3.f = g1h4[(size_t)(sA.w & SRCMASK) * 8 + j3];
            u4.f = g1h4[(size_t)(sB.x & SRCMASK) * 8 + j3];
            u5.f = g1h4[(size_t)(sB.y & SRCMASK) * 8 + j3];
            u6.f = g1h4[(size_t)(sB.z & SRCMASK) * 8 + j3];
            u7.f = g1h4[(size_t)(sB.w & SRCMASK) * 8 + j3];
            #pragma unroll
            for (int t = 0; t < 4; ++t) {
                acc0.h[t] = __hadd2(acc0.h[t], u0.h[t]);
                acc1.h[t] = __hadd2(acc1.h[t], u1.h[t]);
                acc2.h[t] = __hadd2(acc2.h[t], u2.h[t]);
                acc3.h[t] = __hadd2(acc3.h[t], u3.h[t]);
                acc0.h[t] = __hadd2(acc0.h[t], u4.h[t]);
                acc1.h[t] = __hadd2(acc1.h[t], u5.h[t]);
                acc2.h[t] = __hadd2(acc2.h[t], u6.h[t]);
                acc3.h[t] = __hadd2(acc3.h[t], u7.h[t]);
            }
        }
        if (q < nq) {
            int4 sA = cs[q];
            H8 u0, u1, u2, u3;
            u0.f = g1h4[(size_t)(sA.x & SRCMASK) * 8 + j3];
            u1.f = g1h4[(size_t)(sA.y & SRCMASK) * 8 + j3];
            u2.f = g1h4[(size_t)(sA.z & SRCMASK) * 8 + j3];
            u3.f = g1h4[(size_t)(sA.w & SRCMASK) * 8 + j3];
            #pragma unroll
            for (int t = 0; t < 4; ++t) {
                acc0.h[t] = __hadd2(acc0.h[t], u0.h[t]);
                acc1.h[t] = __hadd2(acc1.h[t], u1.h[t]);
                acc2.h[t] = __hadd2(acc2.h[t], u2.h[t]);
                acc3.h[t] = __hadd2(acc3.h[t], u3.h[t]);
            }
        }
        __half2 dih = __float2half2_rn(di);
        #pragma unroll
        for (int t = 0; t < 4; ++t)
            acc0.h[t] = __hmul2(dih, __hadd2(__hadd2(acc0.h[t], acc1.h[t]),
                                             __hadd2(acc2.h[t], acc3.h[t])));
    }
    Hs4[node_l * 9 + j3] = acc0.f;
    __syncthreads();

    int wave = tid >> 6, lane = tid & 63;
    int m = lane & 15, quad = lane >> 4;
    int ncol = wave * 16 + m;
    F4H8 b0, b1;
    const float4* WT4 = (const float4*)wt;
    b0.f = WT4[ncol * 8 + quad];
    b1.f = WT4[ncol * 8 + 4 + quad];
    float bb_  = bias[ncol];
    float wl0 = Wlin[ncol * 2 + 0];
    float wl1 = Wlin[ncol * 2 + 1];
    #pragma unroll
    for (int t = 0; t < 2; ++t) {
        F4H8 a0, a1;
        a0.f = Hs4[(t * 16 + m) * 9 + quad];
        a1.f = Hs4[(t * 16 + m) * 9 + 4 + quad];
        float4_t acc = {0.f, 0.f, 0.f, 0.f};
        acc = __builtin_amdgcn_mfma_f32_16x16x32_f16(a0.h, b0.h, acc, 0, 0, 0);
        acc = __builtin_amdgcn_mfma_f32_16x16x32_f16(a1.h, b1.h, acc, 0, 0, 0);
        #pragma unroll
        for (int reg = 0; reg < 4; ++reg) {
            int row = t * 16 + quad * 4 + reg;
            int grow = row0 + row;
            float h = (grow < N) ? fmaxf(acc[reg] + bb_, 0.0f) : 0.0f;
            float p0 = h * wl0;
            float p1 = h * wl1;
            #pragma unroll
            for (int off = 8; off >= 1; off >>= 1) {   // sum over 16 cols (m)
                p0 += __shfl_xor(p0, off);
                p1 += __shfl_xor(p1, off);
            }
            if (m == 0) {
                lp0[wave * 32 + row] = p0;
                lp1[wave * 32 + row] = p1;
            }
        }
    }
    __syncthreads();
    if (tid < 32) {
        int grow = row0 + tid;
        p0s[tid] = lp0[tid] + lp0[32 + tid] + lp0[64 + tid] + lp0[96 + tid];
        p1s[tid] = lp1[tid] + lp1[32 + tid] + lp1[64 + tid] + lp1[96 + tid];
        bat[tid] = (grow < N) ? batch[grow] : -1;
    }
    __syncthreads();
    if (tid < 32) {
        int bg = bat[tid];
        bool head = (bg >= 0) && (tid == 0 || bat[tid - 1] != bg);
        if (head) {
            float s0 = 0.f, s1 = 0.f;
            for (int k = tid; k < 32 && bat[k] == bg; ++k) {
                s0 += p0s[k];
                s1 += p1s[k];
            }
            atomAddF(&outacc[bg * 2 + 0], s0);
            atomAddF(&outacc[bg * 2 + 1], s1);
        }
    }
}

// counts via binary search on sorted batch; then divide + blin
__global__ void final_kernel(const float* __restrict__ outacc,
                             const int* __restrict__ batch,
                             const float* __restrict__ blin,
                             float* __restrict__ out, int G, int N) {
    int t = blockIdx.x * blockDim.x + threadIdx.x;
    if (t >= G * 2) return;
    int g = t >> 1, c = t & 1;
    int lo = 0, hi = N;
    while (lo < hi) { int m = (lo + hi) >> 1; if (batch[m] < g) lo = m + 1; else hi = m; }
    int lo2 = lo, hi2 = N;
    while (lo2 < hi2) { int m = (lo2 + hi2) >> 1; if (batch[m] < g + 1) lo2 = m + 1; else hi2 = m; }
    float cnt = (float)(lo2 - lo);
    out[t] = outacc[t] / fmaxf(cnt, 1.0f) + blin[c];
}

extern "C" void kernel_launch(void* const* d_in, const int* in_sizes, int n_in,
                              void* d_out, int out_size, void* d_ws, size_t ws_size,
                              hipStream_t stream) {
    const int*   x      = (const int*)d_in[0];
    const int*   ei     = (const int*)d_in[1];   // [2,E] row-major
    const int*   batch  = (const int*)d_in[3];
    const float* table  = (const float*)d_in[4];
    const float* W1     = (const float*)d_in[5];
    const float* b1     = (const float*)d_in[6];
    const float* W2     = (const float*)d_in[7];
    const float* b2     = (const float*)d_in[8];
    const float* Wlin   = (const float*)d_in[9];
    const float* blin   = (const float*)d_in[10];
    float* out = (float*)d_out;

    const int N = in_sizes[0];
    const int E = in_sizes[2];          // edge_type count == E
    const int G = out_size / 2;
    const int TBL = in_sizes[4];        // VOCAB*DD floats

    const int* src = ei;
    const int* dst = ei + E;

    const int K = (N + BKT - 1) / BKT;  // buckets
    const int M = NBLK * MAXK;          // (block, bucket) cells
    const int CH = (E + NBLK - 1) / NBLK;
    const int CSRSZ = E + SLACK * K + 64;

    // workspace layout (keep 16-B alignment for b128 reads)
    __half* g1h     = (__half*)d_ws;                      // (N+1)*64 halves
    __half* th      = g1h + (size_t)(N + 1) * DD;         // TBL halves
    __half* w1t     = th + TBL;                           // 4096 halves
    __half* w2t     = w1t + DD * DD;                      // 4096 halves
    int*    pairbuf = (int*)(w2t + DD * DD);              // E ints
    int*    csr_src = pairbuf + E;                        // CSRSZ ints
    int2*   rowinfo = (int2*)(csr_src + CSRSZ);           // N int2
    float2* xd      = (float2*)(rowinfo + N);             // N+1 float2
    __half* dinvh   = (__half*)(xd + N + 1);              // N+1 halves (pad even)
    float*  outacc  = (float*)(dinvh + (size_t)((N + 2) & ~1)); // 2G
    int*    bb      = (int*)(outacc + 2 * G);             // K+1
    int*    bts     = bb + K + 1;                         // K
    int*    hist    = bts + K;                            // M
    int*    cur     = hist + M;                           // M

    const int BT = 256;

    // partition: per-chunk histogram -> wave-totals(+outacc zero) -> bucket
    //            scan -> per-bucket block scan -> append -> CSR sort
    bin_count_kernel<<<NBLK, BTE, 0, stream>>>(dst, E, CH, hist, K,
                                               (const float2*)table,
                                               (__half2*)th, TBL / 2,
                                               W1, W2, w1t, w2t);
    totals_kernel<<<(K * 64 + BT - 1) / BT, BT, 0, stream>>>(hist, bts, outacc,
                                                             K, 2 * G);
    scan_bb_kernel<<<1, BT, 0, stream>>>(bts, bb, K, E);
    scanB_kernel<<<(K * 64 + BT - 1) / BT, BT, 0, stream>>>(hist, bb, cur, K);
    fill_kernel<<<NBLK, BTE, 0, stream>>>(src, dst, E, CH, cur, pairbuf, K);
    build_csr_kernel<<<K, BT, 0, stream>>>(pairbuf, bb, x, rowinfo, xd, dinvh,
                                           csr_src, g1h, N);

    // layer 1 (embed+agg+MFMA-MLP+relu fused; writes g1h = fp16(dinv*h1))
    int gRow = (N + 31) / 32;
    layer1_kernel<<<gRow, BT, 0, stream>>>(rowinfo, csr_src, xd, dinvh,
                                           (const float4*)th, w1t, b1, g1h, N);
    // layer 2 (agg+MFMA-MLP+relu+pool fused)
    layer2_pool_kernel<<<gRow, BT, 0, stream>>>(rowinfo, csr_src, xd,
                                                (const float4*)g1h, w2t, b2,
                                                batch, Wlin, outacc, N);
    // final
    final_kernel<<<(G * 2 + BT - 1) / BT, BT, 0, stream>>>(outacc, batch, blin,
                                                           out, G, N);
}